// Round 2
// baseline (394.529 us; speedup 1.0000x reference)
//
#include <hip/hip_runtime.h>

// Problem constants (reference: B=32, L=1024, DG=1024, H=1024), all float32.
#define BB 32
#define LL 1024
#define DGG 1024
#define HH 1024
#define ROWS 8   // out rows per block; 8 divides L so all rows in a block share b

// native 4xf32 vector for nontemporal builtins (HIP float4 is a class, rejected)
typedef float f32x4 __attribute__((ext_vector_type(4)));

// gate[b,l] = sigmoid(sum_h query[b,h] * W[h,l] + bias[l])
// grid: (L/64, B), block: 256 = 4 h-groups x 64 lanes.
// Wave n handles h-group n for 64 consecutive l -> W row reads 256B coalesced.
// Est. ~4 us: W tile (4 MB) is L2-resident; latency-bound with unroll-8.
__global__ __launch_bounds__(256) void gate_kernel(
    const float* __restrict__ query,  // [B,H]
    const float* __restrict__ W,      // [H,L]
    const float* __restrict__ bias,   // [L]
    float* __restrict__ gate)         // [B,L] (workspace)
{
    __shared__ float qs[HH];
    __shared__ float partial[4][64];

    const int b  = blockIdx.y;
    const int l0 = blockIdx.x * 64;
    const int t  = threadIdx.x;
    const int ll = t & 63;
    const int hg = t >> 6;            // 0..3, wave-uniform

    for (int h = t; h < HH; h += 256)
        qs[h] = query[b * HH + h];
    __syncthreads();

    const int l = l0 + ll;
    const float* Wp = W + (size_t)(hg * 256) * LL + l;
    float sum = 0.f;
    #pragma unroll 8
    for (int h = 0; h < 256; ++h)
        sum += qs[hg * 256 + h] * Wp[(size_t)h * LL];

    partial[hg][ll] = sum;
    __syncthreads();

    if (t < 64) {
        float s = partial[0][t] + partial[1][t] + partial[2][t] + partial[3][t]
                + bias[l0 + t];
        gate[b * LL + l0 + t] = 1.0f / (1.0f + __expf(-s));
    }
}

// out[b,l, 0:1024]    = gate[b,l] * graph[b,l,:]
// out[b,l, 1024:2048] = query[b,:]
// grid: B*L/ROWS blocks, 256 threads. Each block: ROWS=8 consecutive rows of one
// batch b. Per thread: one query float4 loaded ONCE and stored to all 8 rows;
// 8 graph float4 loads issued back-to-back (8x16B in flight for latency hiding);
// non-temporal stores for the 268 MB streaming output (never re-read here).
__global__ __launch_bounds__(256) void out_kernel(
    const float* __restrict__ graph,  // [B,L,DG]
    const float* __restrict__ query,  // [B,H]
    const float* __restrict__ gate,   // [B,L]
    float* __restrict__ out)          // [B,L,DG+H]
{
    const int blk = blockIdx.x;        // 0 .. B*L/ROWS-1
    const int bl0 = blk * ROWS;        // first (b,l) row of this block
    const int b   = bl0 >> 10;         // L = 1024
    const int t   = threadIdx.x;

    // query float4 for this lane, reused across all ROWS rows (L2-resident, 128 KB total)
    const f32x4 q = reinterpret_cast<const f32x4*>(query)[b * 256 + t];

    const f32x4* gsrc = reinterpret_cast<const f32x4*>(graph) + (size_t)bl0 * 256 + t;
    f32x4*       dst  = reinterpret_cast<f32x4*>(out)         + (size_t)bl0 * 512 + t;

    // gates: uniform per row -> scalar-load friendly, broadcast
    float g[ROWS];
    #pragma unroll
    for (int r = 0; r < ROWS; ++r) g[r] = gate[bl0 + r];

    // issue all graph loads first (MLP: 8 x dwordx4 outstanding)
    f32x4 v[ROWS];
    #pragma unroll
    for (int r = 0; r < ROWS; ++r) v[r] = gsrc[(size_t)r * 256];

    #pragma unroll
    for (int r = 0; r < ROWS; ++r) {
        f32x4 sv = v[r] * g[r];
        __builtin_nontemporal_store(sv, dst + (size_t)r * 512);         // scaled graph
        __builtin_nontemporal_store(q,  dst + (size_t)r * 512 + 256);   // query copy
    }
}

extern "C" void kernel_launch(void* const* d_in, const int* in_sizes, int n_in,
                              void* d_out, int out_size, void* d_ws, size_t ws_size,
                              hipStream_t stream) {
    const float* graph = (const float*)d_in[0]; // [B,L,DG]
    const float* query = (const float*)d_in[1]; // [B,H]
    const float* W     = (const float*)d_in[2]; // [H,L]
    const float* bias  = (const float*)d_in[3]; // [L]
    float* out  = (float*)d_out;
    float* gate = (float*)d_ws;   // B*L f32 = 128 KB scratch

    dim3 g1(LL / 64, BB);
    gate_kernel<<<g1, 256, 0, stream>>>(query, W, bias, gate);
    out_kernel<<<BB * LL / ROWS, 256, 0, stream>>>(graph, query, gate, out);
}

// Round 3
// 386.162 us; speedup vs baseline: 1.0217x; 1.0217x over previous
//
#include <hip/hip_runtime.h>

// Problem constants (reference: B=32, L=1024, DG=1024, H=1024), all float32.
#define BB 32
#define LL 1024
#define DGG 1024
#define HH 1024
#define ROWS 8   // out rows per block; 8 divides L so all rows in a block share b

// native 4xf32 vector (clang ext_vector — also valid for plain loads/stores)
typedef float f32x4 __attribute__((ext_vector_type(4)));

// gate[b,l] = sigmoid(sum_h query[b,h] * W[h,l] + bias[l])
// grid: (L/64, B), block: 256 = 4 h-groups x 64 lanes.
// Wave n handles h-group n for 64 consecutive l -> W row reads 256B coalesced.
// Est. ~4 us: W tile (4 MB) is L2-resident; latency-bound with unroll-8.
__global__ __launch_bounds__(256) void gate_kernel(
    const float* __restrict__ query,  // [B,H]
    const float* __restrict__ W,      // [H,L]
    const float* __restrict__ bias,   // [L]
    float* __restrict__ gate)         // [B,L] (workspace)
{
    __shared__ float qs[HH];
    __shared__ float partial[4][64];

    const int b  = blockIdx.y;
    const int l0 = blockIdx.x * 64;
    const int t  = threadIdx.x;
    const int ll = t & 63;
    const int hg = t >> 6;            // 0..3, wave-uniform

    for (int h = t; h < HH; h += 256)
        qs[h] = query[b * HH + h];
    __syncthreads();

    const int l = l0 + ll;
    const float* Wp = W + (size_t)(hg * 256) * LL + l;
    float sum = 0.f;
    #pragma unroll 8
    for (int h = 0; h < 256; ++h)
        sum += qs[hg * 256 + h] * Wp[(size_t)h * LL];

    partial[hg][ll] = sum;
    __syncthreads();

    if (t < 64) {
        float s = partial[0][t] + partial[1][t] + partial[2][t] + partial[3][t]
                + bias[l0 + t];
        gate[b * LL + l0 + t] = 1.0f / (1.0f + __expf(-s));
    }
}

// out[b,l, 0:1024]    = gate[b,l] * graph[b,l,:]
// out[b,l, 1024:2048] = query[b,:]
// grid: B*L/ROWS blocks, 256 threads. Each block: ROWS=8 consecutive rows of one
// batch b. Per thread: one query float4 loaded ONCE and stored to all 8 rows;
// 8 graph float4 loads issued back-to-back (8x16B in flight for latency hiding).
// REGULAR stores (not nontemporal): retiring the 268 MB streaming write into
// L2/LLC lets the cache defer writeback off this kernel's critical path —
// round-2 A/B showed NT stores cost +18 us by forcing HBM writes in-kernel.
__global__ __launch_bounds__(256) void out_kernel(
    const float* __restrict__ graph,  // [B,L,DG]
    const float* __restrict__ query,  // [B,H]
    const float* __restrict__ gate,   // [B,L]
    float* __restrict__ out)          // [B,L,DG+H]
{
    const int blk = blockIdx.x;        // 0 .. B*L/ROWS-1
    const int bl0 = blk * ROWS;        // first (b,l) row of this block
    const int b   = bl0 >> 10;         // L = 1024
    const int t   = threadIdx.x;

    // query float4 for this lane, reused across all ROWS rows (L2-resident, 128 KB total)
    const f32x4 q = reinterpret_cast<const f32x4*>(query)[b * 256 + t];

    const f32x4* gsrc = reinterpret_cast<const f32x4*>(graph) + (size_t)bl0 * 256 + t;
    f32x4*       dst  = reinterpret_cast<f32x4*>(out)         + (size_t)bl0 * 512 + t;

    // gates: uniform per row -> scalar-load friendly, broadcast
    float g[ROWS];
    #pragma unroll
    for (int r = 0; r < ROWS; ++r) g[r] = gate[bl0 + r];

    // issue all graph loads first (MLP: 8 x dwordx4 outstanding)
    f32x4 v[ROWS];
    #pragma unroll
    for (int r = 0; r < ROWS; ++r) v[r] = gsrc[(size_t)r * 256];

    #pragma unroll
    for (int r = 0; r < ROWS; ++r) {
        dst[(size_t)r * 512]       = v[r] * g[r];   // scaled graph
        dst[(size_t)r * 512 + 256] = q;             // query copy
    }
}

extern "C" void kernel_launch(void* const* d_in, const int* in_sizes, int n_in,
                              void* d_out, int out_size, void* d_ws, size_t ws_size,
                              hipStream_t stream) {
    const float* graph = (const float*)d_in[0]; // [B,L,DG]
    const float* query = (const float*)d_in[1]; // [B,H]
    const float* W     = (const float*)d_in[2]; // [H,L]
    const float* bias  = (const float*)d_in[3]; // [L]
    float* out  = (float*)d_out;
    float* gate = (float*)d_ws;   // B*L f32 = 128 KB scratch

    dim3 g1(LL / 64, BB);
    gate_kernel<<<g1, 256, 0, stream>>>(query, W, bias, gate);
    out_kernel<<<BB * LL / ROWS, 256, 0, stream>>>(graph, query, gate, out);
}

// Round 4
// 376.472 us; speedup vs baseline: 1.0480x; 1.0257x over previous
//
#include <hip/hip_runtime.h>

// Problem constants (reference: B=32, L=1024, DG=1024, H=1024), all float32.
#define BB 32
#define LL 1024
#define DGG 1024
#define HH 1024

// gate[b,l] = sigmoid(sum_h query[b,h] * W[h,l] + bias[l])
// grid: (L/64, B), block: 256 = 4 h-groups x 64 lanes.
// Wave n handles h-group n for 64 consecutive l -> W row reads 256B coalesced.
// ~4 us: W (4 MB) is L2-resident; latency-bound with unroll-8. Off critical path.
__global__ __launch_bounds__(256) void gate_kernel(
    const float* __restrict__ query,  // [B,H]
    const float* __restrict__ W,      // [H,L]
    const float* __restrict__ bias,   // [L]
    float* __restrict__ gate)         // [B,L] (workspace)
{
    __shared__ float qs[HH];
    __shared__ float partial[4][64];

    const int b  = blockIdx.y;
    const int l0 = blockIdx.x * 64;
    const int t  = threadIdx.x;
    const int ll = t & 63;
    const int hg = t >> 6;            // 0..3, wave-uniform

    for (int h = t; h < HH; h += 256)
        qs[h] = query[b * HH + h];
    __syncthreads();

    const int l = l0 + ll;
    const float* Wp = W + (size_t)(hg * 256) * LL + l;
    float sum = 0.f;
    #pragma unroll 8
    for (int h = 0; h < 256; ++h)
        sum += qs[hg * 256 + h] * Wp[(size_t)h * LL];

    partial[hg][ll] = sum;
    __syncthreads();

    if (t < 64) {
        float s = partial[0][t] + partial[1][t] + partial[2][t] + partial[3][t]
                + bias[l0 + t];
        gate[b * LL + l0 + t] = 1.0f / (1.0f + __expf(-s));
    }
}

// out[b,l, 0:1024]    = gate[b,l] * graph[b,l,:]
// out[b,l, 1024:2048] = query[b,:]
// grid: B*L blocks, 256 threads. Each thread: one scaled float4 + one query float4.
// A/B ledger (R0/R2/R3): this 1-row-per-block, cached-store form is fastest.
//  - NT stores: +8 us (forces 268 MB write to HBM in-kernel; cached stores let
//    L2/LLC defer writeback off the critical path).
//  - ROWS=8 batching: +9 us (scatters wave loads to 4 KB stride / stores to
//    8 KB stride; block-contiguous streaming wins for pure BW).
__global__ __launch_bounds__(256) void out_kernel(
    const float* __restrict__ graph,  // [B,L,DG]
    const float* __restrict__ query,  // [B,H]
    const float* __restrict__ gate,   // [B,L]
    float* __restrict__ out)          // [B,L,DG+H]
{
    const int bl = blockIdx.x;        // b*L + l
    const int b  = bl >> 10;
    const int t  = threadIdx.x;
    const float g = gate[bl];

    const float4* gsrc = reinterpret_cast<const float4*>(graph) + (size_t)bl * 256; // 1024 f32 = 256 x float4
    const float4* qsrc = reinterpret_cast<const float4*>(query) + (size_t)b  * 256;
    float4*       dst  = reinterpret_cast<float4*>(out)         + (size_t)bl * 512; // 2048 f32 = 512 x float4

    float4 v = gsrc[t];
    float4 r = make_float4(v.x * g, v.y * g, v.z * g, v.w * g);
    dst[t] = r;
    dst[256 + t] = qsrc[t];
}

extern "C" void kernel_launch(void* const* d_in, const int* in_sizes, int n_in,
                              void* d_out, int out_size, void* d_ws, size_t ws_size,
                              hipStream_t stream) {
    const float* graph = (const float*)d_in[0]; // [B,L,DG]
    const float* query = (const float*)d_in[1]; // [B,H]
    const float* W     = (const float*)d_in[2]; // [H,L]
    const float* bias  = (const float*)d_in[3]; // [L]
    float* out  = (float*)d_out;
    float* gate = (float*)d_ws;   // B*L f32 = 128 KB scratch

    dim3 g1(LL / 64, BB);
    gate_kernel<<<g1, 256, 0, stream>>>(query, W, bias, gate);
    out_kernel<<<BB * LL, 256, 0, stream>>>(graph, query, gate, out);
}